// Round 5
// baseline (94.724 us; speedup 1.0000x reference)
//
#include <hip/hip_runtime.h>

// VLAD pooling: B=16, S=1024, D=512, KC=12, K=10, fp32.
// Ledger: 256 MiB ws poison fill ~43.5 us/iter (unconditional, r1) +
// ~6.6 us single-dispatch residual (r1). Kernel budget is all that's left.
// r1-r4 lesson: hipcc sinks loads to uses (~2-4 in flight) -> cold-HBM
// accum runs at ~50 GB/s/CU (latency-bound, 900cy). Fix: make reads L2-HOT.
// Design: ONE kernel, one block per (b,k) = 160 blocks x 512 thr. Each block
// reads all of feat[b] (2.1 MB); the 10 blocks sharing b are pinned to one
// XCD (bid&7) so feat[b] fits its 4MB L2 -> 9/10 reads are L2 hits at
// ~200-250cy, which a 4-deep pipeline sustains at ~300 GB/s/CU > L2 share.
// Everything (softmax col-k, asum, einsum row, subtract, L2-norm) is
// block-local: zero workspace, zero extra dispatches.

#define B_   16
#define S_   1024
#define D_   512
#define KC_  12
#define K_   10
#define NT   512

__global__ __launch_bounds__(NT) void vlad_fused(
    const float* __restrict__ feat, const float* __restrict__ score,
    const float* __restrict__ cluster, float* __restrict__ out)
{
    // XCD pinning: blocks with the same b land on one XCD (round-robin bid%8)
    const int bid = blockIdx.x;
    const int xcd = bid & 7;
    const int j   = bid >> 3;          // 0..19
    const int b   = xcd * 2 + (j / K_);
    const int k   = j % K_;

    const int tid  = threadIdx.x;
    const int col  = tid & 127;        // float4 column in D
    const int par  = tid >> 7;         // 0..3 s-parity, wave-pair-uniform
    const int lane = tid & 63;
    const int wave = tid >> 6;

    __shared__ __align__(16) float As[S_];   // 4 KB: A[:, k]
    __shared__ float  wred[8];
    __shared__ float  asumS;
    __shared__ float4 red[3][128];           // 6 KB parity partials
    __shared__ float  wsum[2];

    // cluster row fragment for the epilogue (par==0 threads: col==tid)
    float4 cv = make_float4(0.f, 0.f, 0.f, 0.f);
    if (tid < 128)
        cv = ((const float4*)(cluster + (size_t)k * D_))[col];

    // ---- phase 1: softmax column k for pixels tid and tid+512 ----
    float aw = 0.f;
    #pragma unroll
    for (int t = 0; t < 2; t++) {
        const int s = tid + t * NT;
        const float* srow = score + (size_t)(b * S_ + s) * KC_;
        const float4 w0 = ((const float4*)srow)[0];
        const float4 w1 = ((const float4*)srow)[1];
        const float4 w2 = ((const float4*)srow)[2];
        const float  xk = srow[k];       // our column (k is block-uniform)
        float m = fmaxf(fmaxf(fmaxf(w0.x, w0.y), fmaxf(w0.z, w0.w)),
                 fmaxf(fmaxf(fmaxf(w1.x, w1.y), fmaxf(w1.z, w1.w)),
                       fmaxf(fmaxf(w2.x, w2.y), fmaxf(w2.z, w2.w))));
        float sum = __expf(w0.x - m) + __expf(w0.y - m) + __expf(w0.z - m) +
                    __expf(w0.w - m) + __expf(w1.x - m) + __expf(w1.y - m) +
                    __expf(w1.z - m) + __expf(w1.w - m) + __expf(w2.x - m) +
                    __expf(w2.y - m) + __expf(w2.z - m) + __expf(w2.w - m);
        const float a = __expf(xk - m) / sum;
        As[s] = a;
        aw += a;
    }
    // block-reduce aw -> asum (scalar, needed in epilogue)
    #pragma unroll
    for (int off = 32; off > 0; off >>= 1) aw += __shfl_down(aw, off, 64);
    if (lane == 0) wred[wave] = aw;
    __syncthreads();
    if (tid == 0) {
        float s = 0.f;
        #pragma unroll
        for (int w = 0; w < 8; w++) s += wred[w];
        asumS = s;          // read after the phase-3 barrier
    }

    // ---- phase 2: acc[col] = sum_{s in parity} A[s] * feat[b][s][col] ----
    const float4* fp  = (const float4*)(feat + (size_t)(b * S_ + par * 256) * D_) + col;
    const float4* As4 = (const float4*)&As[par * 256];
    float4 acc = make_float4(0.f, 0.f, 0.f, 0.f);
    #pragma unroll 8
    for (int i4 = 0; i4 < 64; i4++) {
        const float4 a4 = As4[i4];               // wave-uniform broadcast
        const float4 v0 = fp[(size_t)(i4 * 4 + 0) * 128];
        const float4 v1 = fp[(size_t)(i4 * 4 + 1) * 128];
        const float4 v2 = fp[(size_t)(i4 * 4 + 2) * 128];
        const float4 v3 = fp[(size_t)(i4 * 4 + 3) * 128];
        acc.x += a4.x * v0.x + a4.y * v1.x + a4.z * v2.x + a4.w * v3.x;
        acc.y += a4.x * v0.y + a4.y * v1.y + a4.z * v2.y + a4.w * v3.y;
        acc.z += a4.x * v0.z + a4.y * v1.z + a4.z * v2.z + a4.w * v3.z;
        acc.w += a4.x * v0.w + a4.y * v1.w + a4.z * v2.w + a4.w * v3.w;
    }

    // ---- phase 3: combine parities, subtract, L2-normalize, store ----
    if (par) red[par - 1][col] = acc;
    __syncthreads();

    float4 r;
    float  sq = 0.f;
    if (!par) {                                   // waves 0,1 (tid < 128)
        const float4 r0 = red[0][col], r1 = red[1][col], r2 = red[2][col];
        const float asv = asumS;
        r.x = acc.x + r0.x + r1.x + r2.x - asv * cv.x;
        r.y = acc.y + r0.y + r1.y + r2.y - asv * cv.y;
        r.z = acc.z + r0.z + r1.z + r2.z - asv * cv.z;
        r.w = acc.w + r0.w + r1.w + r2.w - asv * cv.w;
        sq = r.x * r.x + r.y * r.y + r.z * r.z + r.w * r.w;
        #pragma unroll
        for (int off = 32; off > 0; off >>= 1) sq += __shfl_down(sq, off, 64);
        if (lane == 0) wsum[wave] = sq;
    }
    __syncthreads();
    if (!par) {
        const float tot   = wsum[0] + wsum[1];
        const float scale = rsqrtf(fmaxf(tot, 1e-12f));
        ((float4*)(out + (size_t)(b * K_ + k) * D_))[col] =
            make_float4(r.x * scale, r.y * scale, r.z * scale, r.w * scale);
    }
}

extern "C" void kernel_launch(void* const* d_in, const int* in_sizes, int n_in,
                              void* d_out, int out_size, void* d_ws, size_t ws_size,
                              hipStream_t stream) {
    const float* feat    = (const float*)d_in[0];
    const float* score   = (const float*)d_in[1];
    const float* cluster = (const float*)d_in[2];
    float* out = (float*)d_out;
    (void)d_ws; (void)ws_size;      // no workspace needed

    vlad_fused<<<B_ * K_, NT, 0, stream>>>(feat, score, cluster, out);
}

// Round 8
// 82.382 us; speedup vs baseline: 1.1498x; 1.1498x over previous
//
#include <hip/hip_runtime.h>

// VLAD pooling: B=16, S=1024, D=512, KC=12, K=10, fp32.
// Ledger (measured): 256 MiB ws poison fill ~43.5 us/iter (unconditional) +
// ~4-5 us residual per dispatch. Kernel budget is what remains.
// r5 lesson: 10x feat re-read = 7.9 TB/s cache traffic = cache-BW wall.
// r0-r4 lesson: traffic-minimal shapes were latency-bound at 8 waves/CU
// (~2-4 KB in flight/CU vs ~9.2 KB needed for HBM sat at 900cy).
// Fix: traffic-minimal AND 16 waves/CU AND 8 independent float4 loads/thread.
// (r7 fail was a self-inflicted typo in the asum store index: `+ tid` under
//  tid==0 instead of `+ k`. Fixed here; kernel otherwise identical to r6.)
// K1: 512 blocks (b,c:32-pixel chunk) x 512 thr, 2 blocks/CU (61.5KB LDS).
//     tid = (par 0..3) x (col 0..127 float4). 8 indep float4 loads/thread,
//     acc[k=10][4], parity combine in LDS, coalesced part store.
// K2: 160 blocks (b,k) x 512 thr, tid = (cg 0..3) x (dcol 0..127 float4),
//     8 indep float4 loads/thread, LDS combine, subtract asum*cluster,
//     L2-normalize, store.

#define B_   16
#define S_   1024
#define D_   512
#define KC_  12
#define K_   10
#define CH_  32            // chunks per batch
#define SCH_ (S_ / CH_)    // 32 pixels per chunk
#define NT   512
#define NPAR 4             // pixel parities in K1
#define NPX  (SCH_ / NPAR) // 8 pixels per thread

__global__ __launch_bounds__(NT, 4) void vlad_accum(
    const float* __restrict__ feat, const float* __restrict__ score,
    float* __restrict__ part, float* __restrict__ asum_part)
{
    const int bid = blockIdx.x;
    const int b   = bid >> 5;          // CH_ = 32
    const int c   = bid & (CH_ - 1);
    const int s0  = c * SCH_;
    const int tid = threadIdx.x;
    const int par = tid >> 7;          // 0..3, wave-pair-uniform
    const int col = tid & 127;         // float4 column in D

    __shared__ float  As[SCH_][KC_];            // 1.5 KB
    __shared__ float4 red[NPAR - 1][K_][128];   // 60 KB parity partials

    // ---- softmax: tid<32, one pixel each; asum via 32-lane shuffle ----
    if (tid < SCH_) {
        const float4* sp = (const float4*)(score + (size_t)(b * S_ + s0 + tid) * KC_);
        const float4 w0 = sp[0], w1 = sp[1], w2 = sp[2];
        float x[KC_] = {w0.x, w0.y, w0.z, w0.w, w1.x, w1.y, w1.z, w1.w,
                        w2.x, w2.y, w2.z, w2.w};
        float m = x[0];
        #pragma unroll
        for (int k = 1; k < KC_; k++) m = fmaxf(m, x[k]);
        float sum = 0.f;
        #pragma unroll
        for (int k = 0; k < KC_; k++) { x[k] = __expf(x[k] - m); sum += x[k]; }
        const float inv = 1.0f / sum;
        #pragma unroll
        for (int k = 0; k < KC_; k++) x[k] *= inv;
        *(float4*)&As[tid][0] = make_float4(x[0], x[1], x[2],  x[3]);
        *(float4*)&As[tid][4] = make_float4(x[4], x[5], x[6],  x[7]);
        *(float4*)&As[tid][8] = make_float4(x[8], x[9], x[10], x[11]);
        #pragma unroll
        for (int k = 0; k < K_; k++) {
            float r = x[k];
            r += __shfl_down(r, 16, 32);
            r += __shfl_down(r, 8, 32);
            r += __shfl_down(r, 4, 32);
            r += __shfl_down(r, 2, 32);
            r += __shfl_down(r, 1, 32);
            if (tid == 0) asum_part[(b * CH_ + c) * K_ + k] = r;
        }
    }
    __syncthreads();

    // ---- accumulate: 8 pixels per thread, 8 independent float4 loads ----
    const float4* fp = (const float4*)(feat + (size_t)(b * S_ + s0) * D_) + col;
    float acc[K_][4];
    #pragma unroll
    for (int k = 0; k < K_; k++)
        acc[k][0] = acc[k][1] = acc[k][2] = acc[k][3] = 0.f;

    #pragma unroll
    for (int i = 0; i < NPX; i++) {
        const int s = i * NPAR + par;
        const float4 v  = fp[(size_t)s * 128];
        const float4 a0 = *(const float4*)&As[s][0];   // uniform broadcasts
        const float4 a1 = *(const float4*)&As[s][4];
        const float2 a2 = *(const float2*)&As[s][8];
        const float a[K_] = {a0.x, a0.y, a0.z, a0.w, a1.x, a1.y, a1.z, a1.w,
                             a2.x, a2.y};
        #pragma unroll
        for (int k = 0; k < K_; k++) {
            acc[k][0] += a[k] * v.x;
            acc[k][1] += a[k] * v.y;
            acc[k][2] += a[k] * v.z;
            acc[k][3] += a[k] * v.w;
        }
    }

    // ---- parity combine (par 1..3 -> par 0), coalesced part store ----
    if (par) {
        #pragma unroll
        for (int k = 0; k < K_; k++)
            red[par - 1][k][col] =
                make_float4(acc[k][0], acc[k][1], acc[k][2], acc[k][3]);
    }
    __syncthreads();
    if (!par) {
        float* pp = part + (((size_t)(b * K_) * CH_ + c) * D_) + col * 4;
        #pragma unroll
        for (int k = 0; k < K_; k++) {
            float v0 = acc[k][0], v1 = acc[k][1], v2 = acc[k][2], v3 = acc[k][3];
            #pragma unroll
            for (int p = 0; p < NPAR - 1; p++) {
                const float4 t = red[p][k][col];
                v0 += t.x; v1 += t.y; v2 += t.z; v3 += t.w;
            }
            *(float4*)(pp + (size_t)k * CH_ * D_) = make_float4(v0, v1, v2, v3);
        }
    }
}

// One block per (b,k): 4 chunk-groups x 128 float4 cols, 8 indep loads each.
__global__ __launch_bounds__(NT, 4) void vlad_final(
    const float* __restrict__ part, const float* __restrict__ asum_part,
    const float* __restrict__ cluster, float* __restrict__ out)
{
    const int b    = blockIdx.x / K_;
    const int k    = blockIdx.x % K_;
    const int tid  = threadIdx.x;
    const int cg   = tid >> 7;         // chunk group 0..3 (8 chunks each)
    const int dcol = tid & 127;        // float4 column
    const int lane = tid & 63;
    const int wave = tid >> 6;

    __shared__ float4 red2[3][128];    // 6 KB
    __shared__ float  asumS;
    __shared__ float  wsum2[2];

    // 8 independent float4 loads over this thread's chunk group
    const float4* base =
        (const float4*)(part + (((size_t)(b * K_ + k) * CH_) + cg * 8) * D_) + dcol;
    float4 a = make_float4(0.f, 0.f, 0.f, 0.f);
    #pragma unroll
    for (int cc = 0; cc < 8; cc++) {
        const float4 v = base[(size_t)cc * 128];
        a.x += v.x; a.y += v.y; a.z += v.z; a.w += v.w;
    }

    // asum: tid<32 loads one chunk's value, 32-lane shuffle reduce
    if (tid < 32) {
        float r = asum_part[(b * CH_ + tid) * K_ + k];
        r += __shfl_down(r, 16, 32);
        r += __shfl_down(r, 8, 32);
        r += __shfl_down(r, 4, 32);
        r += __shfl_down(r, 2, 32);
        r += __shfl_down(r, 1, 32);
        if (tid == 0) asumS = r;
    }

    if (cg) red2[cg - 1][dcol] = a;
    __syncthreads();

    float4 r4;
    float  sq = 0.f;
    if (!cg) {                          // tid < 128
        const float4 r0 = red2[0][dcol], r1 = red2[1][dcol], r2 = red2[2][dcol];
        const float4 cv = ((const float4*)(cluster + (size_t)k * D_))[dcol];
        const float asv = asumS;
        r4.x = a.x + r0.x + r1.x + r2.x - asv * cv.x;
        r4.y = a.y + r0.y + r1.y + r2.y - asv * cv.y;
        r4.z = a.z + r0.z + r1.z + r2.z - asv * cv.z;
        r4.w = a.w + r0.w + r1.w + r2.w - asv * cv.w;
        sq = r4.x * r4.x + r4.y * r4.y + r4.z * r4.z + r4.w * r4.w;
        #pragma unroll
        for (int off = 32; off > 0; off >>= 1) sq += __shfl_down(sq, off, 64);
        if (lane == 0) wsum2[wave] = sq;    // waves 0,1
    }
    __syncthreads();
    if (!cg) {
        const float tot   = wsum2[0] + wsum2[1];
        const float scale = rsqrtf(fmaxf(tot, 1e-12f));
        ((float4*)(out + (size_t)(b * K_ + k) * D_))[dcol] =
            make_float4(r4.x * scale, r4.y * scale, r4.z * scale, r4.w * scale);
    }
}

extern "C" void kernel_launch(void* const* d_in, const int* in_sizes, int n_in,
                              void* d_out, int out_size, void* d_ws, size_t ws_size,
                              hipStream_t stream) {
    const float* feat    = (const float*)d_in[0];
    const float* score   = (const float*)d_in[1];
    const float* cluster = (const float*)d_in[2];
    float* out = (float*)d_out;

    float* part      = (float*)d_ws;                        // B*K*CH*D fp32
    float* asum_part = part + (size_t)B_ * K_ * CH_ * D_;   // B*CH*K fp32

    vlad_accum<<<B_ * CH_, NT, 0, stream>>>(feat, score, part, asum_part);
    vlad_final<<<B_ * K_, NT, 0, stream>>>(part, asum_part, cluster, out);
}